// Round 1
// baseline (389.220 us; speedup 1.0000x reference)
//
#include <hip/hip_runtime.h>

#define S_  4096
#define HD_ 64
#define H_  4
#define B_  2
#define DM  256

typedef __bf16 bf16x8 __attribute__((ext_vector_type(8)));
typedef __bf16 bf16x4 __attribute__((ext_vector_type(4)));
typedef float  f32x4  __attribute__((ext_vector_type(4)));

// ---------------- cast f32 -> bf16 (vectorized x4) ----------------
__global__ __launch_bounds__(256) void cast_kernel(const float* __restrict__ src,
                                                   __bf16* __restrict__ dst, int n4) {
    int i = blockIdx.x * 256 + threadIdx.x;
    if (i >= n4) return;
    float4 v = reinterpret_cast<const float4*>(src)[i];
    bf16x4 o = { (__bf16)v.x, (__bf16)v.y, (__bf16)v.z, (__bf16)v.w };
    reinterpret_cast<bf16x4*>(dst)[i] = o;
}

// ---------------- projection GEMM: Y[8192][256] = X @ W^T + bias ----------------
// MODE 0: out bf16 [B][H][S][64]   (Q, K)
// MODE 1: out bf16 [B][H][64][S]   (V transposed)
// MODE 2: out f32  [B*S][256]      (final O projection -> d_out)
template<int MODE>
__global__ __launch_bounds__(256) void proj_kernel(const __bf16* __restrict__ X,
                                                   const __bf16* __restrict__ W,
                                                   const float* __restrict__ bias,
                                                   __bf16* __restrict__ outb,
                                                   float* __restrict__ outf) {
    const int wid  = threadIdx.x >> 6;
    const int lane = threadIdx.x & 63;
    const int g = lane >> 4, c = lane & 15;
    const int m0 = blockIdx.x * 64 + wid * 16;
    const __bf16* Xp = X + (size_t)m0 * DM;

    f32x4 acc[16];
#pragma unroll
    for (int i = 0; i < 16; ++i) acc[i] = (f32x4){0.f, 0.f, 0.f, 0.f};

#pragma unroll
    for (int kf = 0; kf < 8; ++kf) {
        bf16x8 a = *reinterpret_cast<const bf16x8*>(Xp + c * DM + kf * 32 + g * 8);
#pragma unroll
        for (int nt = 0; nt < 16; ++nt) {
            bf16x8 b = *reinterpret_cast<const bf16x8*>(W + (size_t)(nt * 16 + c) * DM + kf * 32 + g * 8);
            acc[nt] = __builtin_amdgcn_mfma_f32_16x16x32_bf16(a, b, acc[nt], 0, 0, 0);
        }
    }

#pragma unroll
    for (int nt = 0; nt < 16; ++nt) {
        const int n = nt * 16 + c;
        const float bs = bias[n];
#pragma unroll
        for (int r = 0; r < 4; ++r) {
            const int m = m0 + g * 4 + r;
            const float v = acc[nt][r] + bs;
            if (MODE == 2) {
                outf[(size_t)m * DM + n] = v;
            } else {
                const int b_ = m >> 12, s = m & (S_ - 1);
                const int h = n >> 6, d = n & 63;
                if (MODE == 0)
                    outb[((size_t)(b_ * H_ + h) * S_ + s) * HD_ + d] = (__bf16)v;
                else
                    outb[((size_t)(b_ * H_ + h) * HD_ + d) * S_ + s] = (__bf16)v;
            }
        }
    }
}

// ---------------- flash attention ----------------
// grid: (B*H, S/64); block 256 = 4 waves; each wave owns 16 q-rows.
__global__ __launch_bounds__(256) void attn_kernel(const __bf16* __restrict__ Q,
                                                   const __bf16* __restrict__ K,
                                                   const __bf16* __restrict__ Vt,
                                                   const int* __restrict__ mask,
                                                   __bf16* __restrict__ AO) {
    __shared__ __bf16 Pl[4][16][72];  // per-wave P tile, padded (stride 144B -> <=2-way conflicts)

    const int bh  = blockIdx.x;     // b*H + h
    const int qt  = blockIdx.y;     // q-tile
    const int wid = threadIdx.x >> 6;
    const int lane = threadIdx.x & 63;
    const int g = lane >> 4, c = lane & 15;
    const int q0 = qt * 64 + wid * 16;

    // Q fragments (A operand), held for whole kernel
    const __bf16* Qp = Q + ((size_t)bh * S_ + q0) * HD_;
    bf16x8 qf0 = *reinterpret_cast<const bf16x8*>(Qp + c * HD_ + g * 8);
    bf16x8 qf1 = *reinterpret_cast<const bf16x8*>(Qp + c * HD_ + 32 + g * 8);

    const __bf16* Kp = K  + (size_t)bh * S_ * HD_;
    const __bf16* Vp = Vt + (size_t)bh * HD_ * S_;

    f32x4 o[4];
#pragma unroll
    for (int i = 0; i < 4; ++i) o[i] = (f32x4){0.f, 0.f, 0.f, 0.f};
    float m2[4] = {-1e30f, -1e30f, -1e30f, -1e30f};
    float l[4]  = {0.f, 0.f, 0.f, 0.f};

    const float SC = 0.125f * 1.44269504088896340736f;  // 1/sqrt(64) * log2(e)

    for (int kb = 0; kb < S_; kb += 64) {
        // ---- S = Q K^T (16 x 64 per wave) ----
        f32x4 s[4];
#pragma unroll
        for (int nt = 0; nt < 4; ++nt) {
            const __bf16* kp = Kp + (size_t)(kb + nt * 16 + c) * HD_ + g * 8;
            bf16x8 k0 = *reinterpret_cast<const bf16x8*>(kp);
            bf16x8 k1 = *reinterpret_cast<const bf16x8*>(kp + 32);
            f32x4 z = (f32x4){0.f, 0.f, 0.f, 0.f};
            s[nt] = __builtin_amdgcn_mfma_f32_16x16x32_bf16(qf0, k0, z, 0, 0, 0);
            s[nt] = __builtin_amdgcn_mfma_f32_16x16x32_bf16(qf1, k1, s[nt], 0, 0, 0);
        }
        // ---- scale to base-2 + mask ----
#pragma unroll
        for (int nt = 0; nt < 4; ++nt) {
#pragma unroll
            for (int r = 0; r < 4; ++r) {
                const int q  = q0 + g * 4 + r;
                const int kk = kb + nt * 16 + c;
                const int mv = mask[(size_t)q * S_ + kk];
                const float t = s[nt][r] * SC;
                s[nt][r] = mv ? t : -6.0e8f;
            }
        }
        // ---- online softmax: row max ----
        float pm[4];
#pragma unroll
        for (int r = 0; r < 4; ++r)
            pm[r] = fmaxf(fmaxf(s[0][r], s[1][r]), fmaxf(s[2][r], s[3][r]));
#pragma unroll
        for (int d = 1; d < 16; d <<= 1) {
#pragma unroll
            for (int r = 0; r < 4; ++r) pm[r] = fmaxf(pm[r], __shfl_xor(pm[r], d));
        }
        float al[4];
#pragma unroll
        for (int r = 0; r < 4; ++r) {
            const float mn = fmaxf(m2[r], pm[r]);
            al[r] = exp2f(m2[r] - mn);
            m2[r] = mn;
        }
        // ---- p = 2^(s - m), row sums ----
        float rs[4] = {0.f, 0.f, 0.f, 0.f};
#pragma unroll
        for (int nt = 0; nt < 4; ++nt) {
#pragma unroll
            for (int r = 0; r < 4; ++r) {
                const float p = exp2f(s[nt][r] - m2[r]);
                s[nt][r] = p;
                rs[r] += p;
            }
        }
#pragma unroll
        for (int d = 1; d < 16; d <<= 1) {
#pragma unroll
            for (int r = 0; r < 4; ++r) rs[r] += __shfl_xor(rs[r], d);
        }
#pragma unroll
        for (int r = 0; r < 4; ++r) l[r] = l[r] * al[r] + rs[r];
        // ---- rescale O ----
#pragma unroll
        for (int nt = 0; nt < 4; ++nt)
#pragma unroll
            for (int r = 0; r < 4; ++r) o[nt][r] *= al[r];
        // ---- P -> LDS (C layout) ----
#pragma unroll
        for (int nt = 0; nt < 4; ++nt)
#pragma unroll
            for (int r = 0; r < 4; ++r)
                Pl[wid][g * 4 + r][nt * 16 + c] = (__bf16)s[nt][r];
        // ---- P A-fragments from LDS (wave-private region; compiler orders DS ops) ----
        bf16x8 pa0 = *reinterpret_cast<const bf16x8*>(&Pl[wid][c][g * 8]);
        bf16x8 pa1 = *reinterpret_cast<const bf16x8*>(&Pl[wid][c][32 + g * 8]);
        // ---- O += P V ----
#pragma unroll
        for (int nt = 0; nt < 4; ++nt) {
            const __bf16* vp = Vp + (size_t)(nt * 16 + c) * S_ + kb + g * 8;
            bf16x8 v0 = *reinterpret_cast<const bf16x8*>(vp);
            bf16x8 v1 = *reinterpret_cast<const bf16x8*>(vp + 32);
            o[nt] = __builtin_amdgcn_mfma_f32_16x16x32_bf16(pa0, v0, o[nt], 0, 0, 0);
            o[nt] = __builtin_amdgcn_mfma_f32_16x16x32_bf16(pa1, v1, o[nt], 0, 0, 0);
        }
    }

    // ---- epilogue: O / l -> AO[b][s][h*64+d] bf16 ----
    const int b_ = bh >> 2, h = bh & 3;
#pragma unroll
    for (int nt = 0; nt < 4; ++nt) {
        const int d = nt * 16 + c;
#pragma unroll
        for (int r = 0; r < 4; ++r) {
            const int q = q0 + g * 4 + r;
            AO[((size_t)b_ * S_ + q) * DM + h * HD_ + d] = (__bf16)(o[nt][r] / l[r]);
        }
    }
}

// ---------------- launch ----------------
extern "C" void kernel_launch(void* const* d_in, const int* in_sizes, int n_in,
                              void* d_out, int out_size, void* d_ws, size_t ws_size,
                              hipStream_t stream) {
    const float* x_logic  = (const float*)d_in[0];
    const float* x_memory = (const float*)d_in[1];
    const int*   mask     = (const int*)d_in[2];
    const float* Wq = (const float*)d_in[3];
    const float* bq = (const float*)d_in[4];
    const float* Wk = (const float*)d_in[5];
    const float* bk = (const float*)d_in[6];
    const float* Wv = (const float*)d_in[7];
    const float* bv = (const float*)d_in[8];
    const float* Wo = (const float*)d_in[9];
    const float* bo = (const float*)d_in[10];
    float* out = (float*)d_out;

    char* ws = (char*)d_ws;
    size_t off = 0;
    auto alloc = [&](size_t bytes) { char* p = ws + off; off += (bytes + 255) & ~255ull; return p; };

    const size_t NX = (size_t)B_ * S_ * DM;   // 2M elements
    __bf16* xl  = (__bf16*)alloc(NX * 2);
    __bf16* xm  = (__bf16*)alloc(NX * 2);
    __bf16* wq  = (__bf16*)alloc((size_t)DM * DM * 2);
    __bf16* wk  = (__bf16*)alloc((size_t)DM * DM * 2);
    __bf16* wv  = (__bf16*)alloc((size_t)DM * DM * 2);
    __bf16* wo  = (__bf16*)alloc((size_t)DM * DM * 2);
    __bf16* Qb  = (__bf16*)alloc(NX * 2);
    __bf16* Kb  = (__bf16*)alloc(NX * 2);
    __bf16* Vtb = (__bf16*)alloc(NX * 2);
    __bf16* AO  = (__bf16*)alloc(NX * 2);

    // casts
    cast_kernel<<<(int)(NX / 4 + 255) / 256, 256, 0, stream>>>(x_logic, xl, (int)(NX / 4));
    cast_kernel<<<(int)(NX / 4 + 255) / 256, 256, 0, stream>>>(x_memory, xm, (int)(NX / 4));
    cast_kernel<<<(DM * DM / 4 + 255) / 256, 256, 0, stream>>>(Wq, wq, DM * DM / 4);
    cast_kernel<<<(DM * DM / 4 + 255) / 256, 256, 0, stream>>>(Wk, wk, DM * DM / 4);
    cast_kernel<<<(DM * DM / 4 + 255) / 256, 256, 0, stream>>>(Wv, wv, DM * DM / 4);
    cast_kernel<<<(DM * DM / 4 + 255) / 256, 256, 0, stream>>>(Wo, wo, DM * DM / 4);

    // projections
    proj_kernel<0><<<128, 256, 0, stream>>>(xl, wq, bq, Qb, nullptr);
    proj_kernel<0><<<128, 256, 0, stream>>>(xl, wk, bk, Kb, nullptr);
    proj_kernel<1><<<128, 256, 0, stream>>>(xm, wv, bv, Vtb, nullptr);

    // attention
    attn_kernel<<<dim3(8, 64), 256, 0, stream>>>(Qb, Kb, Vtb, mask, AO);

    // output projection -> f32
    proj_kernel<2><<<128, 256, 0, stream>>>(AO, wo, bo, nullptr, out);
}

// Round 2
// 325.418 us; speedup vs baseline: 1.1961x; 1.1961x over previous
//
#include <hip/hip_runtime.h>

#define S_  4096
#define HD_ 64
#define H_  4
#define B_  2
#define DM  256
#define NS  2                 // split-K factor for attention
#define KSPAN (S_ / NS)

typedef __bf16 bf16x8 __attribute__((ext_vector_type(8)));
typedef __bf16 bf16x4 __attribute__((ext_vector_type(4)));
typedef float  f32x4  __attribute__((ext_vector_type(4)));
typedef unsigned long long u64;

// ---------------- prep: pack mask to bits + cast weights to bf16 ----------------
// blocks [0,1024): mask packing.  packed[(kk>>6)*S + q] bit i = mask[q][ (kk&~63) + i ]
// blocks [1024,1088): cast Wq,Wk,Wv,Wo (each 256x256 f32) to bf16.
__global__ __launch_bounds__(256) void prep_kernel(const int* __restrict__ mask,
                                                   u64* __restrict__ packed,
                                                   const float* __restrict__ Wq,
                                                   const float* __restrict__ Wk,
                                                   const float* __restrict__ Wv,
                                                   const float* __restrict__ Wo,
                                                   __bf16* __restrict__ wqb,
                                                   __bf16* __restrict__ wkb,
                                                   __bf16* __restrict__ wvb,
                                                   __bf16* __restrict__ wob) {
    const int bid = blockIdx.x;
    if (bid < 1024) {
        const int gw   = bid * 4 + (threadIdx.x >> 6);   // global wave id [0,4096)
        const int lane = threadIdx.x & 63;
        for (int step = 0; step < 64; ++step) {
            const int wi  = gw + step * 4096;            // word index [0, 262144)
            const int kbb = wi >> 12;                    // wi / S_
            const int q   = wi & (S_ - 1);
            const int mv  = mask[(size_t)q * S_ + kbb * 64 + lane];
            const u64 bits = __ballot(mv != 0);
            if (lane == 0) packed[wi] = bits;
        }
    } else {
        const int t = (bid - 1024) * 256 + threadIdx.x;  // [0,16384)
        for (int i = t; i < 65536; i += 16384) {
            const int arr = i >> 14, idx = i & 16383;
            const float* src = arr == 0 ? Wq : arr == 1 ? Wk : arr == 2 ? Wv : Wo;
            __bf16* dst      = arr == 0 ? wqb : arr == 1 ? wkb : arr == 2 ? wvb : wob;
            float4 v = reinterpret_cast<const float4*>(src)[idx];
            bf16x4 o = { (__bf16)v.x, (__bf16)v.y, (__bf16)v.z, (__bf16)v.w };
            reinterpret_cast<bf16x4*>(dst)[idx] = o;
        }
    }
}

// ---------------- QKV projection: reads f32 X, bf16 W ----------------
// blockIdx.y: 0=Q (scaled by 1/8*log2e), 1=K, 2=V(transposed out)
__global__ __launch_bounds__(256) void proj_qkv_kernel(const float* __restrict__ xl,
                                                       const float* __restrict__ xm,
                                                       const __bf16* __restrict__ wq,
                                                       const __bf16* __restrict__ wk,
                                                       const __bf16* __restrict__ wv,
                                                       const float* __restrict__ bq,
                                                       const float* __restrict__ bk,
                                                       const float* __restrict__ bv,
                                                       __bf16* __restrict__ Qb,
                                                       __bf16* __restrict__ Kb,
                                                       __bf16* __restrict__ Vtb) {
    const int mode = blockIdx.y;
    const float*  X    = (mode == 2) ? xm : xl;
    const __bf16* W    = (mode == 0) ? wq : (mode == 1) ? wk : wv;
    const float*  bias = (mode == 0) ? bq : (mode == 1) ? bk : bv;
    const float scale  = (mode == 0) ? 0.18033688011112042f : 1.0f; // 0.125*log2(e)

    const int wid  = threadIdx.x >> 6;
    const int lane = threadIdx.x & 63;
    const int g = lane >> 4, c = lane & 15;
    const int m0 = blockIdx.x * 64 + wid * 16;
    const float* Xp = X + (size_t)m0 * DM;

    f32x4 acc[16];
#pragma unroll
    for (int i = 0; i < 16; ++i) acc[i] = (f32x4){0.f, 0.f, 0.f, 0.f};

#pragma unroll
    for (int kf = 0; kf < 8; ++kf) {
        const float* ap = Xp + c * DM + kf * 32 + g * 8;
        float4 u0 = *reinterpret_cast<const float4*>(ap);
        float4 u1 = *reinterpret_cast<const float4*>(ap + 4);
        bf16x8 a = { (__bf16)u0.x, (__bf16)u0.y, (__bf16)u0.z, (__bf16)u0.w,
                     (__bf16)u1.x, (__bf16)u1.y, (__bf16)u1.z, (__bf16)u1.w };
#pragma unroll
        for (int nt = 0; nt < 16; ++nt) {
            bf16x8 b = *reinterpret_cast<const bf16x8*>(W + (size_t)(nt * 16 + c) * DM + kf * 32 + g * 8);
            acc[nt] = __builtin_amdgcn_mfma_f32_16x16x32_bf16(a, b, acc[nt], 0, 0, 0);
        }
    }

#pragma unroll
    for (int nt = 0; nt < 16; ++nt) {
        const int n = nt * 16 + c;
        const float bs = bias[n];
        const int h = n >> 6, d = n & 63;
#pragma unroll
        for (int r = 0; r < 4; ++r) {
            const int m = m0 + g * 4 + r;
            const float v = (acc[nt][r] + bs) * scale;
            const int b_ = m >> 12, s = m & (S_ - 1);
            if (mode == 0)
                Qb[((size_t)(b_ * H_ + h) * S_ + s) * HD_ + d] = (__bf16)v;
            else if (mode == 1)
                Kb[((size_t)(b_ * H_ + h) * S_ + s) * HD_ + d] = (__bf16)v;
            else
                Vtb[((size_t)(b_ * H_ + h) * HD_ + d) * S_ + s] = (__bf16)v;
        }
    }
}

// ---------------- flash attention, no-max base-2 softmax, split-K ----------------
// grid: (B*H, NS, S/64); block 256 = 4 waves; wave owns 16 q-rows, k range [sp*KSPAN, ...)
__global__ __launch_bounds__(256) void attn_kernel(const __bf16* __restrict__ Q,
                                                   const __bf16* __restrict__ K,
                                                   const __bf16* __restrict__ Vt,
                                                   const u64* __restrict__ packed,
                                                   float* __restrict__ Opart,
                                                   float* __restrict__ Lpart) {
    __shared__ __bf16 Pl[4][16][72];

    const int bh = blockIdx.x;
    const int sp = blockIdx.y;
    const int qt = blockIdx.z;
    const int wid  = threadIdx.x >> 6;
    const int lane = threadIdx.x & 63;
    const int g = lane >> 4, c = lane & 15;
    const int q0 = qt * 64 + wid * 16;

    const __bf16* Qp = Q + ((size_t)bh * S_ + q0) * HD_;
    bf16x8 qf0 = *reinterpret_cast<const bf16x8*>(Qp + c * HD_ + g * 8);
    bf16x8 qf1 = *reinterpret_cast<const bf16x8*>(Qp + c * HD_ + 32 + g * 8);

    const __bf16* Kp = K  + (size_t)bh * S_ * HD_;
    const __bf16* Vp = Vt + (size_t)bh * HD_ * S_;

    f32x4 o[4];
#pragma unroll
    for (int i = 0; i < 4; ++i) o[i] = (f32x4){0.f, 0.f, 0.f, 0.f};
    float rs[4] = {0.f, 0.f, 0.f, 0.f};

    const int k0 = sp * KSPAN, k1 = k0 + KSPAN;
    for (int kb = k0; kb < k1; kb += 64) {
        const int kbb = kb >> 6;
        // mask words: 4 rows (broadcast across the 16 c-lanes)
        const u64* mwp = packed + (size_t)kbb * S_ + q0 + g * 4;
        u64 mw0 = mwp[0], mw1 = mwp[1], mw2 = mwp[2], mw3 = mwp[3];
        unsigned lo[4] = { (unsigned)mw0, (unsigned)mw1, (unsigned)mw2, (unsigned)mw3 };
        unsigned hi[4] = { (unsigned)(mw0 >> 32), (unsigned)(mw1 >> 32),
                           (unsigned)(mw2 >> 32), (unsigned)(mw3 >> 32) };

        // ---- S = Q K^T (16 x 64 per wave); Q pre-scaled ----
        f32x4 s[4];
#pragma unroll
        for (int nt = 0; nt < 4; ++nt) {
            const __bf16* kp = Kp + (size_t)(kb + nt * 16 + c) * HD_ + g * 8;
            bf16x8 kA = *reinterpret_cast<const bf16x8*>(kp);
            bf16x8 kB = *reinterpret_cast<const bf16x8*>(kp + 32);
            f32x4 z = (f32x4){0.f, 0.f, 0.f, 0.f};
            s[nt] = __builtin_amdgcn_mfma_f32_16x16x32_bf16(qf0, kA, z, 0, 0, 0);
            s[nt] = __builtin_amdgcn_mfma_f32_16x16x32_bf16(qf1, kB, s[nt], 0, 0, 0);
        }

        // ---- p = 2^s * maskbit; accumulate row sums; P -> LDS ----
#pragma unroll
        for (int nt = 0; nt < 4; ++nt) {
            const unsigned sh = (nt & 1) * 16 + c;
#pragma unroll
            for (int r = 0; r < 4; ++r) {
                const unsigned w = (nt < 2) ? lo[r] : hi[r];
                const unsigned bit = (w >> sh) & 1u;
                float p = exp2f(s[nt][r]);
                p = bit ? p : 0.0f;
                rs[r] += p;
                Pl[wid][g * 4 + r][nt * 16 + c] = (__bf16)p;
            }
        }

        bf16x8 pa0 = *reinterpret_cast<const bf16x8*>(&Pl[wid][c][g * 8]);
        bf16x8 pa1 = *reinterpret_cast<const bf16x8*>(&Pl[wid][c][32 + g * 8]);

        // ---- O += P V ----
#pragma unroll
        for (int nt = 0; nt < 4; ++nt) {
            const __bf16* vp = Vp + (size_t)(nt * 16 + c) * S_ + kb + g * 8;
            bf16x8 v0 = *reinterpret_cast<const bf16x8*>(vp);
            bf16x8 v1 = *reinterpret_cast<const bf16x8*>(vp + 32);
            o[nt] = __builtin_amdgcn_mfma_f32_16x16x32_bf16(pa0, v0, o[nt], 0, 0, 0);
            o[nt] = __builtin_amdgcn_mfma_f32_16x16x32_bf16(pa1, v1, o[nt], 0, 0, 0);
        }
    }

    // ---- epilogue: write partial O and l ----
#pragma unroll
    for (int d = 1; d < 16; d <<= 1) {
#pragma unroll
        for (int r = 0; r < 4; ++r) rs[r] += __shfl_xor(rs[r], d);
    }
    const size_t obase = ((size_t)(bh * NS + sp) * S_ + q0) * 64;
#pragma unroll
    for (int nt = 0; nt < 4; ++nt) {
#pragma unroll
        for (int r = 0; r < 4; ++r)
            Opart[obase + (size_t)(g * 4 + r) * 64 + nt * 16 + c] = o[nt][r];
    }
    if (c == 0) {
#pragma unroll
        for (int r = 0; r < 4; ++r)
            Lpart[(size_t)(bh * NS + sp) * S_ + q0 + g * 4 + r] = rs[r];
    }
}

// ---------------- O projection with in-register split-K merge ----------------
__global__ __launch_bounds__(256) void proj_o_kernel(const float* __restrict__ Opart,
                                                     const float* __restrict__ Lpart,
                                                     const __bf16* __restrict__ wo,
                                                     const float* __restrict__ bo,
                                                     float* __restrict__ out) {
    const int wid  = threadIdx.x >> 6;
    const int lane = threadIdx.x & 63;
    const int g = lane >> 4, c = lane & 15;
    const int m0 = blockIdx.x * 64 + wid * 16;

    const int row = m0 + c;                    // A-fragment row
    const int b_ = row >> 12, s = row & (S_ - 1);

    f32x4 acc[16];
#pragma unroll
    for (int i = 0; i < 16; ++i) acc[i] = (f32x4){0.f, 0.f, 0.f, 0.f};

#pragma unroll
    for (int kf = 0; kf < 8; ++kf) {
        const int dcol = kf * 32 + g * 8;
        const int h = dcol >> 6, dm = dcol & 63;
        const int bh = b_ * H_ + h;
        const float l = Lpart[(size_t)(bh * NS + 0) * S_ + s] +
                        Lpart[(size_t)(bh * NS + 1) * S_ + s];
        const float invl = 1.0f / l;
        const size_t base0 = ((size_t)(bh * NS + 0) * S_ + s) * 64 + dm;
        const size_t base1 = ((size_t)(bh * NS + 1) * S_ + s) * 64 + dm;
        float4 p00 = *reinterpret_cast<const float4*>(Opart + base0);
        float4 p01 = *reinterpret_cast<const float4*>(Opart + base0 + 4);
        float4 p10 = *reinterpret_cast<const float4*>(Opart + base1);
        float4 p11 = *reinterpret_cast<const float4*>(Opart + base1 + 4);
        bf16x8 a = { (__bf16)((p00.x + p10.x) * invl), (__bf16)((p00.y + p10.y) * invl),
                     (__bf16)((p00.z + p10.z) * invl), (__bf16)((p00.w + p10.w) * invl),
                     (__bf16)((p01.x + p11.x) * invl), (__bf16)((p01.y + p11.y) * invl),
                     (__bf16)((p01.z + p11.z) * invl), (__bf16)((p01.w + p11.w) * invl) };
#pragma unroll
        for (int nt = 0; nt < 16; ++nt) {
            bf16x8 b = *reinterpret_cast<const bf16x8*>(wo + (size_t)(nt * 16 + c) * DM + kf * 32 + g * 8);
            acc[nt] = __builtin_amdgcn_mfma_f32_16x16x32_bf16(a, b, acc[nt], 0, 0, 0);
        }
    }

#pragma unroll
    for (int nt = 0; nt < 16; ++nt) {
        const int n = nt * 16 + c;
        const float bs = bo[n];
#pragma unroll
        for (int r = 0; r < 4; ++r) {
            const int m = m0 + g * 4 + r;
            out[(size_t)m * DM + n] = acc[nt][r] + bs;
        }
    }
}

// ---------------- launch ----------------
extern "C" void kernel_launch(void* const* d_in, const int* in_sizes, int n_in,
                              void* d_out, int out_size, void* d_ws, size_t ws_size,
                              hipStream_t stream) {
    const float* x_logic  = (const float*)d_in[0];
    const float* x_memory = (const float*)d_in[1];
    const int*   mask     = (const int*)d_in[2];
    const float* Wq = (const float*)d_in[3];
    const float* bq = (const float*)d_in[4];
    const float* Wk = (const float*)d_in[5];
    const float* bk = (const float*)d_in[6];
    const float* Wv = (const float*)d_in[7];
    const float* bv = (const float*)d_in[8];
    const float* Wo = (const float*)d_in[9];
    const float* bo = (const float*)d_in[10];
    float* out = (float*)d_out;

    char* ws = (char*)d_ws;
    size_t off = 0;
    auto alloc = [&](size_t bytes) { char* p = ws + off; off += (bytes + 255) & ~255ull; return p; };

    const size_t NX = (size_t)B_ * S_ * DM;   // 2M elements
    __bf16* wqb = (__bf16*)alloc((size_t)DM * DM * 2);
    __bf16* wkb = (__bf16*)alloc((size_t)DM * DM * 2);
    __bf16* wvb = (__bf16*)alloc((size_t)DM * DM * 2);
    __bf16* wob = (__bf16*)alloc((size_t)DM * DM * 2);
    u64*    packed = (u64*)alloc((size_t)S_ * (S_ / 64) * 8);      // 2 MB
    __bf16* Qb  = (__bf16*)alloc(NX * 2);
    __bf16* Kb  = (__bf16*)alloc(NX * 2);
    __bf16* Vtb = (__bf16*)alloc(NX * 2);
    float*  Opart = (float*)alloc((size_t)B_ * H_ * NS * S_ * HD_ * 4);  // 16 MB
    float*  Lpart = (float*)alloc((size_t)B_ * H_ * NS * S_ * 4);        // 256 KB

    prep_kernel<<<1088, 256, 0, stream>>>(mask, packed, Wq, Wk, Wv, Wo, wqb, wkb, wvb, wob);
    proj_qkv_kernel<<<dim3(128, 3), 256, 0, stream>>>(x_logic, x_memory, wqb, wkb, wvb,
                                                      bq, bk, bv, Qb, Kb, Vtb);
    attn_kernel<<<dim3(8, NS, 64), 256, 0, stream>>>(Qb, Kb, Vtb, packed, Opart, Lpart);
    proj_o_kernel<<<128, 256, 0, stream>>>(Opart, Lpart, wob, bo, out);
}

// Round 3
// 161.887 us; speedup vs baseline: 2.4043x; 2.0102x over previous
//
#include <hip/hip_runtime.h>

#define S_  4096
#define HD_ 64
#define H_  4
#define B_  2
#define DM  256
#define NS  2                 // split-K factor for attention
#define KSPAN (S_ / NS)
#define NITER (KSPAN / 64)

typedef __bf16 bf16x8 __attribute__((ext_vector_type(8)));
typedef __bf16 bf16x4 __attribute__((ext_vector_type(4)));
typedef float  f32x4  __attribute__((ext_vector_type(4)));
typedef unsigned long long u64;

// ---------------- prep: pack mask to bits + cast weights to bf16 ----------------
__global__ __launch_bounds__(256) void prep_kernel(const int* __restrict__ mask,
                                                   u64* __restrict__ packed,
                                                   const float* __restrict__ Wq,
                                                   const float* __restrict__ Wk,
                                                   const float* __restrict__ Wv,
                                                   const float* __restrict__ Wo,
                                                   __bf16* __restrict__ wqb,
                                                   __bf16* __restrict__ wkb,
                                                   __bf16* __restrict__ wvb,
                                                   __bf16* __restrict__ wob) {
    const int bid = blockIdx.x;
    if (bid < 1024) {
        const int gw   = bid * 4 + (threadIdx.x >> 6);   // global wave id [0,4096)
        const int lane = threadIdx.x & 63;
        for (int step = 0; step < 64; ++step) {
            const int wi  = gw + step * 4096;            // word index [0, 262144)
            const int kbb = wi >> 12;                    // wi / S_
            const int q   = wi & (S_ - 1);
            const int mv  = mask[(size_t)q * S_ + kbb * 64 + lane];
            const u64 bits = __ballot(mv != 0);
            if (lane == 0) packed[wi] = bits;
        }
    } else {
        const int t = (bid - 1024) * 256 + threadIdx.x;  // [0,16384)
        for (int i = t; i < 65536; i += 16384) {
            const int arr = i >> 14, idx = i & 16383;
            const float* src = arr == 0 ? Wq : arr == 1 ? Wk : arr == 2 ? Wv : Wo;
            __bf16* dst      = arr == 0 ? wqb : arr == 1 ? wkb : arr == 2 ? wvb : wob;
            float4 v = reinterpret_cast<const float4*>(src)[idx];
            bf16x4 o = { (__bf16)v.x, (__bf16)v.y, (__bf16)v.z, (__bf16)v.w };
            reinterpret_cast<bf16x4*>(dst)[idx] = o;
        }
    }
}

// ---------------- QKV projection: reads f32 X, bf16 W ----------------
__global__ __launch_bounds__(256) void proj_qkv_kernel(const float* __restrict__ xl,
                                                       const float* __restrict__ xm,
                                                       const __bf16* __restrict__ wq,
                                                       const __bf16* __restrict__ wk,
                                                       const __bf16* __restrict__ wv,
                                                       const float* __restrict__ bq,
                                                       const float* __restrict__ bk,
                                                       const float* __restrict__ bv,
                                                       __bf16* __restrict__ Qb,
                                                       __bf16* __restrict__ Kb,
                                                       __bf16* __restrict__ Vtb) {
    const int mode = blockIdx.y;
    const float*  X    = (mode == 2) ? xm : xl;
    const __bf16* W    = (mode == 0) ? wq : (mode == 1) ? wk : wv;
    const float*  bias = (mode == 0) ? bq : (mode == 1) ? bk : bv;
    const float scale  = (mode == 0) ? 0.18033688011112042f : 1.0f; // 0.125*log2(e)

    const int wid  = threadIdx.x >> 6;
    const int lane = threadIdx.x & 63;
    const int g = lane >> 4, c = lane & 15;
    const int m0 = blockIdx.x * 64 + wid * 16;
    const float* Xp = X + (size_t)m0 * DM;

    f32x4 acc[16];
#pragma unroll
    for (int i = 0; i < 16; ++i) acc[i] = (f32x4){0.f, 0.f, 0.f, 0.f};

#pragma unroll
    for (int kf = 0; kf < 8; ++kf) {
        const float* ap = Xp + c * DM + kf * 32 + g * 8;
        float4 u0 = *reinterpret_cast<const float4*>(ap);
        float4 u1 = *reinterpret_cast<const float4*>(ap + 4);
        bf16x8 a = { (__bf16)u0.x, (__bf16)u0.y, (__bf16)u0.z, (__bf16)u0.w,
                     (__bf16)u1.x, (__bf16)u1.y, (__bf16)u1.z, (__bf16)u1.w };
#pragma unroll
        for (int nt = 0; nt < 16; ++nt) {
            bf16x8 b = *reinterpret_cast<const bf16x8*>(W + (size_t)(nt * 16 + c) * DM + kf * 32 + g * 8);
            acc[nt] = __builtin_amdgcn_mfma_f32_16x16x32_bf16(a, b, acc[nt], 0, 0, 0);
        }
    }

#pragma unroll
    for (int nt = 0; nt < 16; ++nt) {
        const int n = nt * 16 + c;
        const float bs = bias[n];
        const int h = n >> 6, d = n & 63;
#pragma unroll
        for (int r = 0; r < 4; ++r) {
            const int m = m0 + g * 4 + r;
            const float v = (acc[nt][r] + bs) * scale;
            const int b_ = m >> 12, s = m & (S_ - 1);
            if (mode == 0)
                Qb[((size_t)(b_ * H_ + h) * S_ + s) * HD_ + d] = (__bf16)v;
            else if (mode == 1)
                Kb[((size_t)(b_ * H_ + h) * S_ + s) * HD_ + d] = (__bf16)v;
            else
                Vtb[((size_t)(b_ * H_ + h) * HD_ + d) * S_ + s] = (__bf16)v;
        }
    }
}

// ---------------- flash attention: swapped QK^T, LDS-staged K/V, reg-prefetch ----------------
// grid: (B*H, NS, 64); block 256 = 4 waves; each wave owns 16 q-rows.
__global__ __launch_bounds__(256, 4) void attn_kernel(const __bf16* __restrict__ Q,
                                                      const __bf16* __restrict__ K,
                                                      const __bf16* __restrict__ Vt,
                                                      const u64* __restrict__ packed,
                                                      float* __restrict__ Opart,
                                                      float* __restrict__ Lpart) {
    __shared__ __bf16 Kt[64][72];      // [kk][d], rows padded to 144B
    __shared__ __bf16 Vl[64][72];      // [d][kk]
    __shared__ __bf16 Pl[4][16][72];   // per-wave P [q][kk]

    const int bh = blockIdx.x;
    const int sp = blockIdx.y;
    const int qt = blockIdx.z;
    const int tid  = threadIdx.x;
    const int wid  = tid >> 6;
    const int lane = tid & 63;
    const int g = lane >> 4, c = lane & 15;
    const int q0w = qt * 64 + wid * 16;

    // Q B-fragments (col=q, k=d), held for whole kernel
    const __bf16* Qp = Q + ((size_t)bh * S_ + q0w) * HD_;
    bf16x8 qb0 = *reinterpret_cast<const bf16x8*>(Qp + c * HD_ + g * 8);
    bf16x8 qb1 = *reinterpret_cast<const bf16x8*>(Qp + c * HD_ + 32 + g * 8);

    const __bf16* Kp = K  + (size_t)bh * S_ * HD_;
    const __bf16* Vp = Vt + (size_t)bh * HD_ * S_;

    // staging assignment: thread loads 32B of one row (K: row=kk, V: row=d)
    const int srow = tid >> 2;            // 0..63
    const int sseg = (tid & 3) * 16;      // element col base

    f32x4 o[4];
#pragma unroll
    for (int i = 0; i < 4; ++i) o[i] = (f32x4){0.f, 0.f, 0.f, 0.f};
    float rs = 0.f;

    const int k0 = sp * KSPAN;

    bf16x8 kr0, kr1, vr0, vr1;
    // prologue: load + write first tile
    {
        const __bf16* krow = Kp + (size_t)(k0 + srow) * HD_ + sseg;
        const __bf16* vrow = Vp + (size_t)srow * S_ + k0 + sseg;
        kr0 = *reinterpret_cast<const bf16x8*>(krow);
        kr1 = *reinterpret_cast<const bf16x8*>(krow + 8);
        vr0 = *reinterpret_cast<const bf16x8*>(vrow);
        vr1 = *reinterpret_cast<const bf16x8*>(vrow + 8);
        *reinterpret_cast<bf16x8*>(&Kt[srow][sseg])     = kr0;
        *reinterpret_cast<bf16x8*>(&Kt[srow][sseg + 8]) = kr1;
        *reinterpret_cast<bf16x8*>(&Vl[srow][sseg])     = vr0;
        *reinterpret_cast<bf16x8*>(&Vl[srow][sseg + 8]) = vr1;
    }
    __syncthreads();

    for (int it = 0; it < NITER; ++it) {
        const int kb = k0 + it * 64;
        const bool more = (it + 1 < NITER);
        // T14: issue next tile's global loads early
        if (more) {
            const __bf16* krow = Kp + (size_t)(kb + 64 + srow) * HD_ + sseg;
            const __bf16* vrow = Vp + (size_t)srow * S_ + kb + 64 + sseg;
            kr0 = *reinterpret_cast<const bf16x8*>(krow);
            kr1 = *reinterpret_cast<const bf16x8*>(krow + 8);
            vr0 = *reinterpret_cast<const bf16x8*>(vrow);
            vr1 = *reinterpret_cast<const bf16x8*>(vrow + 8);
        }

        // mask word for this lane's q row
        const u64 mw = packed[(size_t)(kb >> 6) * S_ + q0w + c];
        const unsigned wlo = (unsigned)mw, whi = (unsigned)(mw >> 32);

        // ---- S^T = K Q^T : st[nt] covers kk=nt*16..+15 x q=0..15 ----
        f32x4 st[4];
#pragma unroll
        for (int nt = 0; nt < 4; ++nt) {
            bf16x8 ka0 = *reinterpret_cast<const bf16x8*>(&Kt[nt * 16 + c][g * 8]);
            bf16x8 ka1 = *reinterpret_cast<const bf16x8*>(&Kt[nt * 16 + c][32 + g * 8]);
            f32x4 z = (f32x4){0.f, 0.f, 0.f, 0.f};
            st[nt] = __builtin_amdgcn_mfma_f32_16x16x32_bf16(ka0, qb0, z, 0, 0, 0);
            st[nt] = __builtin_amdgcn_mfma_f32_16x16x32_bf16(ka1, qb1, st[nt], 0, 0, 0);
        }

        // ---- p = 2^s * bit (lane holds kk = nt*16+g*4+r for q=c) ----
#pragma unroll
        for (int nt = 0; nt < 4; ++nt) {
            const unsigned w = (nt < 2) ? wlo : whi;
            const unsigned base = (nt & 1) * 16 + g * 4;
            float p0 = ((w >> (base + 0)) & 1u) ? exp2f(st[nt][0]) : 0.f;
            float p1 = ((w >> (base + 1)) & 1u) ? exp2f(st[nt][1]) : 0.f;
            float p2 = ((w >> (base + 2)) & 1u) ? exp2f(st[nt][2]) : 0.f;
            float p3 = ((w >> (base + 3)) & 1u) ? exp2f(st[nt][3]) : 0.f;
            rs += (p0 + p1) + (p2 + p3);
            bf16x4 pw = { (__bf16)p0, (__bf16)p1, (__bf16)p2, (__bf16)p3 };
            *reinterpret_cast<bf16x4*>(&Pl[wid][c][nt * 16 + g * 4]) = pw;
        }

        // ---- P A-fragments (row=q=c, k=kk) ----
        bf16x8 pa0 = *reinterpret_cast<const bf16x8*>(&Pl[wid][c][g * 8]);
        bf16x8 pa1 = *reinterpret_cast<const bf16x8*>(&Pl[wid][c][32 + g * 8]);

        // ---- O += P V ----
#pragma unroll
        for (int nt = 0; nt < 4; ++nt) {
            bf16x8 vb0 = *reinterpret_cast<const bf16x8*>(&Vl[nt * 16 + c][g * 8]);
            bf16x8 vb1 = *reinterpret_cast<const bf16x8*>(&Vl[nt * 16 + c][32 + g * 8]);
            o[nt] = __builtin_amdgcn_mfma_f32_16x16x32_bf16(pa0, vb0, o[nt], 0, 0, 0);
            o[nt] = __builtin_amdgcn_mfma_f32_16x16x32_bf16(pa1, vb1, o[nt], 0, 0, 0);
        }

        __syncthreads();
        if (more) {
            *reinterpret_cast<bf16x8*>(&Kt[srow][sseg])     = kr0;
            *reinterpret_cast<bf16x8*>(&Kt[srow][sseg + 8]) = kr1;
            *reinterpret_cast<bf16x8*>(&Vl[srow][sseg])     = vr0;
            *reinterpret_cast<bf16x8*>(&Vl[srow][sseg + 8]) = vr1;
            __syncthreads();
        }
    }

    // ---- epilogue ----
    rs += __shfl_xor(rs, 16);
    rs += __shfl_xor(rs, 32);
    if (lane < 16)
        Lpart[(size_t)(bh * NS + sp) * S_ + q0w + c] = rs;

    const size_t obase = ((size_t)(bh * NS + sp) * S_ + q0w) * 64;
#pragma unroll
    for (int nt = 0; nt < 4; ++nt) {
#pragma unroll
        for (int r = 0; r < 4; ++r)
            Opart[obase + (size_t)(g * 4 + r) * 64 + nt * 16 + c] = o[nt][r];
    }
}

// ---------------- O projection with in-register split-K merge ----------------
__global__ __launch_bounds__(256) void proj_o_kernel(const float* __restrict__ Opart,
                                                     const float* __restrict__ Lpart,
                                                     const __bf16* __restrict__ wo,
                                                     const float* __restrict__ bo,
                                                     float* __restrict__ out) {
    const int wid  = threadIdx.x >> 6;
    const int lane = threadIdx.x & 63;
    const int g = lane >> 4, c = lane & 15;
    const int m0 = blockIdx.x * 64 + wid * 16;

    const int row = m0 + c;                    // A-fragment row
    const int b_ = row >> 12, s = row & (S_ - 1);

    f32x4 acc[16];
#pragma unroll
    for (int i = 0; i < 16; ++i) acc[i] = (f32x4){0.f, 0.f, 0.f, 0.f};

#pragma unroll
    for (int kf = 0; kf < 8; ++kf) {
        const int dcol = kf * 32 + g * 8;
        const int h = dcol >> 6, dm = dcol & 63;
        const int bh = b_ * H_ + h;
        const float l = Lpart[(size_t)(bh * NS + 0) * S_ + s] +
                        Lpart[(size_t)(bh * NS + 1) * S_ + s];
        const float invl = 1.0f / l;
        const size_t base0 = ((size_t)(bh * NS + 0) * S_ + s) * 64 + dm;
        const size_t base1 = ((size_t)(bh * NS + 1) * S_ + s) * 64 + dm;
        float4 p00 = *reinterpret_cast<const float4*>(Opart + base0);
        float4 p01 = *reinterpret_cast<const float4*>(Opart + base0 + 4);
        float4 p10 = *reinterpret_cast<const float4*>(Opart + base1);
        float4 p11 = *reinterpret_cast<const float4*>(Opart + base1 + 4);
        bf16x8 a = { (__bf16)((p00.x + p10.x) * invl), (__bf16)((p00.y + p10.y) * invl),
                     (__bf16)((p00.z + p10.z) * invl), (__bf16)((p00.w + p10.w) * invl),
                     (__bf16)((p01.x + p11.x) * invl), (__bf16)((p01.y + p11.y) * invl),
                     (__bf16)((p01.z + p11.z) * invl), (__bf16)((p01.w + p11.w) * invl) };
#pragma unroll
        for (int nt = 0; nt < 16; ++nt) {
            bf16x8 b = *reinterpret_cast<const bf16x8*>(wo + (size_t)(nt * 16 + c) * DM + kf * 32 + g * 8);
            acc[nt] = __builtin_amdgcn_mfma_f32_16x16x32_bf16(a, b, acc[nt], 0, 0, 0);
        }
    }

#pragma unroll
    for (int nt = 0; nt < 16; ++nt) {
        const int n = nt * 16 + c;
        const float bs = bo[n];
#pragma unroll
        for (int r = 0; r < 4; ++r) {
            const int m = m0 + g * 4 + r;
            out[(size_t)m * DM + n] = acc[nt][r] + bs;
        }
    }
}

// ---------------- launch ----------------
extern "C" void kernel_launch(void* const* d_in, const int* in_sizes, int n_in,
                              void* d_out, int out_size, void* d_ws, size_t ws_size,
                              hipStream_t stream) {
    const float* x_logic  = (const float*)d_in[0];
    const float* x_memory = (const float*)d_in[1];
    const int*   mask     = (const int*)d_in[2];
    const float* Wq = (const float*)d_in[3];
    const float* bq = (const float*)d_in[4];
    const float* Wk = (const float*)d_in[5];
    const float* bk = (const float*)d_in[6];
    const float* Wv = (const float*)d_in[7];
    const float* bv = (const float*)d_in[8];
    const float* Wo = (const float*)d_in[9];
    const float* bo = (const float*)d_in[10];
    float* out = (float*)d_out;

    char* ws = (char*)d_ws;
    size_t off = 0;
    auto alloc = [&](size_t bytes) { char* p = ws + off; off += (bytes + 255) & ~255ull; return p; };

    const size_t NX = (size_t)B_ * S_ * DM;   // 2M elements
    __bf16* wqb = (__bf16*)alloc((size_t)DM * DM * 2);
    __bf16* wkb = (__bf16*)alloc((size_t)DM * DM * 2);
    __bf16* wvb = (__bf16*)alloc((size_t)DM * DM * 2);
    __bf16* wob = (__bf16*)alloc((size_t)DM * DM * 2);
    u64*    packed = (u64*)alloc((size_t)S_ * (S_ / 64) * 8);      // 2 MB
    __bf16* Qb  = (__bf16*)alloc(NX * 2);
    __bf16* Kb  = (__bf16*)alloc(NX * 2);
    __bf16* Vtb = (__bf16*)alloc(NX * 2);
    float*  Opart = (float*)alloc((size_t)B_ * H_ * NS * S_ * HD_ * 4);  // 16 MB
    float*  Lpart = (float*)alloc((size_t)B_ * H_ * NS * S_ * 4);        // 256 KB

    prep_kernel<<<1088, 256, 0, stream>>>(mask, packed, Wq, Wk, Wv, Wo, wqb, wkb, wvb, wob);
    proj_qkv_kernel<<<dim3(128, 3), 256, 0, stream>>>(x_logic, x_memory, wqb, wkb, wvb,
                                                      bq, bk, bv, Qb, Kb, Vtb);
    attn_kernel<<<dim3(8, NS, 64), 256, 0, stream>>>(Qb, Kb, Vtb, packed, Opart, Lpart);
    proj_o_kernel<<<128, 256, 0, stream>>>(Opart, Lpart, wob, bo, out);
}